// Round 10
// baseline (363.883 us; speedup 1.0000x reference)
//
#include <hip/hip_runtime.h>
#include <hip/hip_bf16.h>
#include <hip/hip_cooperative_groups.h>
#include <stdint.h>

namespace cg = cooperative_groups;

#define B_ 16
#define N_ 512
#define E_ 8192
#define D_ 256
#define NBUCKET (B_ * N_)          // bucket per (batch, dst node) = 8192
#define CAP 64                     // records per bucket (mean 8, 11-sigma safe)

// ---- workspace layout (float offsets) ----
constexpr int OFF_VE  = 16;
constexpr int OFF_VEP = OFF_VE + D_;              // 32 x 256 v_edge partials
constexpr int OFF_TN  = OFF_VEP + 32 * D_;
constexpr int OFF_S1  = OFF_TN + B_*N_*D_;
constexpr int OFF_S2  = OFF_S1 + NBUCKET;
constexpr int OFF_SC  = OFF_S2 + NBUCKET;
constexpr int OFF_SM  = OFF_SC + B_*E_;           // 32 floats: per-batch M, 1/S
constexpr int OFF_CNT = OFF_SM + 32;              // 8192 ints
constexpr int OFF_REC = OFF_CNT + NBUCKET;        // int x NBUCKET*CAP (2 MB)

__device__ __forceinline__ float bf2f(uint16_t u) {
    union { uint32_t i; float f; } v; v.i = ((uint32_t)u) << 16; return v.f;
}

__device__ __forceinline__ float loadF(const void* p, int i, int isBF) {
    if (isBF) return __bfloat162float(((const __hip_bfloat16*)p)[i]);
    return ((const float*)p)[i];
}

__device__ __forceinline__ float4 loadF4(const void* p, int i, int isBF) {
    if (isBF) {
        ushort4 v = *(const ushort4*)((const uint16_t*)p + i);
        return make_float4(bf2f(v.x), bf2f(v.y), bf2f(v.z), bf2f(v.w));
    }
    return *(const float4*)((const float*)p + i);
}

// mask layouts: 0=u8/bool, 1=int32, 2=bf16, 3=f32
__device__ __forceinline__ bool readMask(const void* p, int i, int ml) {
    if (ml == 0) return ((const uint8_t*)p)[i] != 0;
    if (ml == 1) return ((const int*)p)[i] != 0;
    if (ml == 2) return (((const uint16_t*)p)[i] & 0x7FFFu) != 0;
    return (((const uint32_t*)p)[i] & 0x7FFFFFFFu) != 0;
}

// Inline dtype/mask-layout detection: pure function of fixed input words
// (wave-uniform broadcast loads, L2-hot after the first wave).
__device__ __forceinline__ void detect(const void* obj, const void* emask,
                                       int& isBF, int& ml) {
    const uint32_t* ow = (const uint32_t*)obj;
    int insane = 0;
    #pragma unroll
    for (int i = 0; i < 32; ++i) {
        uint32_t x = ow[i];
        uint32_t lo = x & 0xFFFFu, hi = x >> 16;
        uint32_t el = (lo >> 7) & 0xFFu, eh = (hi >> 7) & 0xFFu;
        if ((lo & 0x7FFFu) && (el < 107u || el > 147u)) insane++;
        if ((hi & 0x7FFFu) && (eh < 107u || eh > 147u)) insane++;
    }
    isBF = (insane >= 8) ? 0 : 1;   // f32 -> ~27/64 insane halfwords; bf16 -> ~0
    const uint32_t* ew = (const uint32_t*)emask;
    bool i32ok = true, f32ok = true, bfok = true;
    #pragma unroll
    for (int i = 0; i < 16; ++i) {
        uint32_t x = ew[i];
        if (x > 1u) i32ok = false;
        if (x != 0u && x != 0x3F800000u) f32ok = false;
        uint32_t lo = x & 0xFFFFu, hi = x >> 16;
        if (!((lo == 0u || lo == 0x3F80u) && (hi == 0u || hi == 0x3F80u))) bfok = false;
    }
    ml = i32ok ? 1 : (f32ok ? 3 : (bfok ? 2 : 0));
}

// ---- single cooperative mega-kernel: all phases, 4 grid syncs ----
__global__ __launch_bounds__(256, 4) void k_mega(
    const void* obj, const void* pred, const int2* rel, const void* sim,
    const void* nmask, const void* emask, const void* wn, const void* we,
    const void* wa, const void* gam, const void* bet, float* ws, void* out)
{
    cg::grid_group gg = cg::this_grid();
    __shared__ float As[32][68];
    __shared__ float Bs[32][68];

    int isBF, ml;
    detect(obj, emask, isBF, ml);

    const int t = threadIdx.x;
    const int nb = gridDim.x;
    const int nthr = nb * 256;
    const int gid = blockIdx.x * 256 + t;
    const int wid = gid >> 6, lane = gid & 63;
    const int nwaves = nthr >> 6;

    // ---- Phase A: v_edge partials (blocks 0..31) + zero CNT/S1/S2 ----
    if (blockIdx.x < 32) {
        int d0 = blockIdx.x * 8;
        float a = 0.f;
        #pragma unroll
        for (int i = 0; i < 8; ++i)
            a += loadF(wa, 513 + d0 + i, isBF) * loadF(we, (d0 + i) * D_ + t, isBF);
        ws[OFF_VEP + blockIdx.x * D_ + t] = a;
    }
    for (int i = gid; i < 3 * NBUCKET; i += nthr) {
        int j = i;
        if (j < NBUCKET) { ((int*)ws)[OFF_CNT + j] = 0; continue; }
        j -= NBUCKET;
        if (j < NBUCKET) { ws[OFF_S1 + j] = 0.f; continue; }
        ws[OFF_S2 + j - NBUCKET] = 0.f;
    }
    gg.sync();

    // ---- Phase B: node_fc SGEMM (grid-stride tiles) + s1/s2 + VE reduce ----
    if (blockIdx.x == nb - 1) {
        float a = 0.f;
        #pragma unroll
        for (int p = 0; p < 32; ++p) a += ws[OFF_VEP + p * D_ + t];
        ws[OFF_VE + t] = a;
    }
    {
        float* tn = ws + OFF_TN;
        const int tx = t & 15, ty = t >> 4;
        const int sr = t >> 2, sk = (t & 3) * 8;
        for (int tile = blockIdx.x; tile < 512; tile += nb) {
            int bm = tile >> 2, bn = tile & 3;
            int row0 = bm * 64, col0 = bn * 64;
            float acc[4][4] = {};
            for (int kt = 0; kt < 8; ++kt) {
                int k0 = kt * 32;
                __syncthreads();
                float4 a0 = loadF4(obj, (row0 + sr) * D_ + k0 + sk, isBF);
                float4 a1 = loadF4(obj, (row0 + sr) * D_ + k0 + sk + 4, isBF);
                float4 b0 = loadF4(wn, (col0 + sr) * D_ + k0 + sk, isBF);
                float4 b1 = loadF4(wn, (col0 + sr) * D_ + k0 + sk + 4, isBF);
                As[sk+0][sr] = a0.x; As[sk+1][sr] = a0.y; As[sk+2][sr] = a0.z; As[sk+3][sr] = a0.w;
                As[sk+4][sr] = a1.x; As[sk+5][sr] = a1.y; As[sk+6][sr] = a1.z; As[sk+7][sr] = a1.w;
                Bs[sk+0][sr] = b0.x; Bs[sk+1][sr] = b0.y; Bs[sk+2][sr] = b0.z; Bs[sk+3][sr] = b0.w;
                Bs[sk+4][sr] = b1.x; Bs[sk+5][sr] = b1.y; Bs[sk+6][sr] = b1.z; Bs[sk+7][sr] = b1.w;
                __syncthreads();
                #pragma unroll
                for (int k = 0; k < 32; ++k) {
                    float4 av = *(const float4*)&As[k][ty * 4];
                    float4 bv = *(const float4*)&Bs[k][tx * 4];
                    acc[0][0] += av.x * bv.x; acc[0][1] += av.x * bv.y;
                    acc[0][2] += av.x * bv.z; acc[0][3] += av.x * bv.w;
                    acc[1][0] += av.y * bv.x; acc[1][1] += av.y * bv.y;
                    acc[1][2] += av.y * bv.z; acc[1][3] += av.y * bv.w;
                    acc[2][0] += av.z * bv.x; acc[2][1] += av.z * bv.y;
                    acc[2][2] += av.z * bv.z; acc[2][3] += av.z * bv.w;
                    acc[3][0] += av.w * bv.x; acc[3][1] += av.w * bv.y;
                    acc[3][2] += av.w * bv.z; acc[3][3] += av.w * bv.w;
                }
            }
            #pragma unroll
            for (int rr = 0; rr < 4; ++rr) {
                float4 o = make_float4(acc[rr][0], acc[rr][1], acc[rr][2], acc[rr][3]);
                *(float4*)&tn[(size_t)(row0 + ty * 4 + rr) * D_ + col0 + tx * 4] = o;
            }
            float w1v[4], w2v[4];
            #pragma unroll
            for (int c = 0; c < 4; ++c) {
                w1v[c] = loadF(wa, col0 + tx * 4 + c, isBF);
                w2v[c] = loadF(wa, D_ + col0 + tx * 4 + c, isBF);
            }
            #pragma unroll
            for (int rr = 0; rr < 4; ++rr) {
                float p1 = acc[rr][0]*w1v[0] + acc[rr][1]*w1v[1] + acc[rr][2]*w1v[2] + acc[rr][3]*w1v[3];
                float p2 = acc[rr][0]*w2v[0] + acc[rr][1]*w2v[1] + acc[rr][2]*w2v[2] + acc[rr][3]*w2v[3];
                #pragma unroll
                for (int o = 1; o < 16; o <<= 1) {
                    p1 += __shfl_xor(p1, o);
                    p2 += __shfl_xor(p2, o);
                }
                if (tx == 0) {
                    atomicAdd(&ws[OFF_S1 + row0 + ty * 4 + rr], p1);
                    atomicAdd(&ws[OFF_S2 + row0 + ty * 4 + rr], p2);
                }
            }
        }
    }
    gg.sync();

    // ---- Phase C: edge scores (wave per edge, grid-stride) + bucket fill ----
    {
        float4 ve4 = *(const float4*)(ws + OFF_VE + lane * 4);
        float simc = loadF(wa, 512, isBF);
        for (int e = wid; e < B_ * E_; e += nwaves) {
            bool m = readMask(emask, e, ml);   // wave-uniform
            if (!m) {
                if (lane == 0) ws[OFF_SC + e] = -1e9f;
                continue;
            }
            int b = e >> 13;
            float dot;
            if (isBF) {
                ushort4 v = *(const ushort4*)((const uint16_t*)pred + (size_t)e * D_ + lane * 4);
                dot = bf2f(v.x)*ve4.x + bf2f(v.y)*ve4.y + bf2f(v.z)*ve4.z + bf2f(v.w)*ve4.w;
            } else {
                float4 v = *(const float4*)((const float*)pred + (size_t)e * D_ + lane * 4);
                dot = v.x*ve4.x + v.y*ve4.y + v.z*ve4.z + v.w*ve4.w;
            }
            #pragma unroll
            for (int off = 32; off > 0; off >>= 1) dot += __shfl_xor(dot, off);
            if (lane == 0) {
                int2 sd = rel[e];
                float s = dot + ws[OFF_S1 + b * N_ + sd.x] + ws[OFF_S2 + b * N_ + sd.y]
                        + loadF(sim, e, isBF) * simc;
                s = (s > 0.f) ? s : 0.01f * s;         // leaky_relu
                ws[OFF_SC + e] = s;
                int bucket = b * N_ + sd.y;
                int slot = atomicAdd((int*)ws + OFF_CNT + bucket, 1);
                if (slot < CAP)
                    ((int*)ws)[OFF_REC + bucket * CAP + slot] = sd.x | ((e & (E_ - 1)) << 16);
            }
        }
    }
    gg.sync();

    // ---- Phase D: per-batch softmax stats (blocks 0..15) ----
    for (int b = blockIdx.x; b < B_; b += nb) {
        float* red = (float*)As;               // reuse GEMM LDS
        const float* sc = ws + OFF_SC + b * E_;
        float mx = -3e38f;
        for (int i = t * 4; i < E_; i += 1024) {
            float4 v = *(const float4*)(sc + i);
            mx = fmaxf(fmaxf(mx, fmaxf(v.x, v.y)), fmaxf(v.z, v.w));
        }
        #pragma unroll
        for (int o = 32; o > 0; o >>= 1) mx = fmaxf(mx, __shfl_xor(mx, o));
        __syncthreads();
        if ((t & 63) == 0) red[t >> 6] = mx;
        __syncthreads();
        float M = fmaxf(fmaxf(red[0], red[1]), fmaxf(red[2], red[3]));
        float sum = 0.f;
        for (int i = t * 4; i < E_; i += 1024) {
            float4 v = *(const float4*)(sc + i);
            sum += __expf(v.x - M) + __expf(v.y - M) + __expf(v.z - M) + __expf(v.w - M);
        }
        #pragma unroll
        for (int o = 32; o > 0; o >>= 1) sum += __shfl_xor(sum, o);
        __syncthreads();
        if ((t & 63) == 0) red[t >> 6] = sum;
        __syncthreads();
        if (t == 0) {
            float S = red[0] + red[1] + red[2] + red[3];
            ws[OFF_SM + b * 2]     = M;
            ws[OFF_SM + b * 2 + 1] = 1.f / S;
        }
    }
    gg.sync();

    // ---- Phase E: wave per (batch,node): register accum + mask + LayerNorm ----
    for (int ng = wid; ng < NBUCKET; ng += nwaves) {
        int b = ng >> 9;
        int cnt = ((const int*)ws)[OFF_CNT + ng];
        if (cnt > CAP) cnt = CAP;
        const int* rec = (const int*)ws + OFF_REC + ng * CAP;
        const float* tnb = ws + OFF_TN + (size_t)b * N_ * D_;
        const float* scb = ws + OFF_SC + b * E_;
        float M    = ws[OFF_SM + b * 2];
        float invS = ws[OFF_SM + b * 2 + 1];
        float v0 = 0.f, v1 = 0.f, v2 = 0.f, v3 = 0.f;
        for (int i = 0; i < cnt; ++i) {
            int rc = rec[i];
            int src = rc & 0xFFFF;
            float wv = __expf(scb[((unsigned)rc) >> 16] - M) * invS;
            const float* s = tnb + (size_t)src * D_;
            v0 += wv * s[lane];
            v1 += wv * s[lane + 64];
            v2 += wv * s[lane + 128];
            v3 += wv * s[lane + 192];
        }
        float mk = readMask(nmask, ng, ml) ? 1.f : 0.f;
        v0 *= mk; v1 *= mk; v2 *= mk; v3 *= mk;
        float sum = v0 + v1 + v2 + v3;
        float sq  = v0*v0 + v1*v1 + v2*v2 + v3*v3;
        #pragma unroll
        for (int o = 32; o > 0; o >>= 1) {
            sum += __shfl_xor(sum, o);
            sq  += __shfl_xor(sq, o);
        }
        float mu  = sum * (1.f / 256.f);
        float var = fmaxf(sq * (1.f / 256.f) - mu * mu, 0.f);
        float rs  = rsqrtf(var + 1e-5f);
        size_t ro = (size_t)ng * D_;
        float g0 = loadF(gam, lane,       isBF), c0 = loadF(bet, lane,       isBF);
        float g1 = loadF(gam, lane + 64,  isBF), c1 = loadF(bet, lane + 64,  isBF);
        float g2 = loadF(gam, lane + 128, isBF), c2 = loadF(bet, lane + 128, isBF);
        float g3 = loadF(gam, lane + 192, isBF), c3 = loadF(bet, lane + 192, isBF);
        float r0 = (v0 - mu) * rs * g0 + c0;
        float r1 = (v1 - mu) * rs * g1 + c1;
        float r2 = (v2 - mu) * rs * g2 + c2;
        float r3 = (v3 - mu) * rs * g3 + c3;
        if (isBF) {
            __hip_bfloat16* o = (__hip_bfloat16*)out + ro;
            o[lane]       = __float2bfloat16(r0);
            o[lane + 64]  = __float2bfloat16(r1);
            o[lane + 128] = __float2bfloat16(r2);
            o[lane + 192] = __float2bfloat16(r3);
        } else {
            float* o = (float*)out + ro;
            o[lane] = r0; o[lane + 64] = r1; o[lane + 128] = r2; o[lane + 192] = r3;
        }
    }
}

extern "C" void kernel_launch(void* const* d_in, const int* in_sizes, int n_in,
                              void* d_out, int out_size, void* d_ws, size_t ws_size,
                              hipStream_t stream) {
    (void)in_sizes; (void)n_in; (void)out_size; (void)ws_size;
    const void* obj   = d_in[0];
    const void* pred  = d_in[1];
    const int2* rel   = (const int2*)d_in[2];
    const void* sim   = d_in[3];
    const void* nmask = d_in[4];
    const void* emask = d_in[5];
    const void* wn    = d_in[6];
    const void* we    = d_in[7];
    const void* wa    = d_in[8];
    const void* gam   = d_in[9];
    const void* bet   = d_in[10];
    float* ws = (float*)d_ws;
    void* outp = d_out;

    int maxB = 0;
    hipOccupancyMaxActiveBlocksPerMultiprocessor(&maxB, (const void*)k_mega, 256, 0);
    int dev = 0, cus = 256;
    hipGetDevice(&dev);
    hipDeviceGetAttribute(&cus, hipDeviceAttributeMultiprocessorCount, dev);
    int grid = maxB * cus;
    if (grid > 1024) grid = 1024;       // 4 blocks/CU target; co-residency guaranteed

    void* args[] = { &obj, &pred, &rel, &sim, &nmask, &emask,
                     &wn, &we, &wa, &gam, &bet, &ws, &outp };
    hipLaunchCooperativeKernel((void*)k_mega, dim3(grid), dim3(256), args, 0, stream);
}